// Round 3
// baseline (1122.838 us; speedup 1.0000x reference)
//
#include <hip/hip_runtime.h>
#include <hip/hip_bf16.h>

typedef __hip_bfloat16 bf16;

__device__ __forceinline__ float b2f(bf16 v) { return __bfloat162float(v); }
__device__ __forceinline__ bf16  f2b(float v) { return __float2bfloat16(v); }

// dtype-flexible input load: F32=1 -> float*, F32=0 -> bf16*
template<int F32>
__device__ __forceinline__ float ldin(const void* p, size_t i) {
  if (F32) return ((const float*)p)[i];
  return b2f(((const bf16*)p)[i]);
}

// ---------------------------------------------------------------------------
// dtype detector: bf16 N(0,1) data never has exponent field >= 0x90 (|x|>=2^17);
// fp32-as-u16 low halves are random -> ~44% exceed it. flag=1 means fp32.
// ---------------------------------------------------------------------------
__global__ void k_detect(const unsigned short* __restrict__ u, int* __restrict__ flag)
{
  if (threadIdx.x == 0 && blockIdx.x == 0) {
    int nbad = 0;
    for (int i = 0; i < 256; i++) {
      unsigned e = (u[i] >> 7) & 0xFFu;
      nbad += (e >= 0x90u) ? 1 : 0;
    }
    flag[0] = (nbad > 8) ? 1 : 0;
  }
}

// ---------------------------------------------------------------------------
// conv1 band: band[n][oc64][l][x512] = relu(conv3x3 s2 p1(image)), global row
// g = g0+l; rows outside [0,512) written as ZERO (conv2's zero padding).
// grid: x = L blocks (L/2 row-pairs x 2 x-chunks), y = oc group(2), z = net(2)
// ---------------------------------------------------------------------------
template<int F32>
__global__ __launch_bounds__(256) void k_conv1_band(
    const void* __restrict__ in0, const void* __restrict__ in1,
    const void* __restrict__ w0,  const void* __restrict__ bi0,
    const void* __restrict__ w1,  const void* __restrict__ bi1,
    bf16* __restrict__ band, const int* __restrict__ flag, int g0, int L)
{
  if (flag[0] != F32) return;                    // uniform across device
  const int n  = blockIdx.z;
  const int og = blockIdx.y;
  const void* IN = n ? in1 : in0;                // n=0 style/snet, n=1 content/cnet
  const void* W  = n ? w1  : w0;
  const void* B  = n ? bi1 : bi0;

  __shared__ __align__(16) float wl[27][32];
  __shared__ float bl[32];
  const int tid = threadIdx.x;
  for (int i = tid; i < 864; i += 256) {
    int ocl = i & 31, kk = i >> 5;
    wl[kk][ocl] = ldin<F32>(W, (size_t)(og * 32 + ocl) * 27 + kk);
  }
  if (tid < 32) bl[tid] = ldin<F32>(B, og * 32 + tid);
  __syncthreads();

  const int bx = blockIdx.x;
  const int rp = bx >> 1, xc = bx & 1;
  const int ox = xc * 256 + tid;                 // 0..511
  const int l0 = rp * 2;
  const int ga = g0 + l0;

  float a0[32], a1[32];
  #pragma unroll
  for (int j = 0; j < 32; j++) { a0[j] = bl[j]; a1[j] = bl[j]; }

  for (int ic = 0; ic < 3; ic++) {
    const size_t icb = (size_t)ic * 1048576;
    float iv[5][3];
    #pragma unroll
    for (int rr = 0; rr < 5; rr++) {
      int iy = 2 * ga - 1 + rr;
      bool oky = (unsigned)iy < 1024u;
      #pragma unroll
      for (int kx = 0; kx < 3; kx++) {
        int ix = 2 * ox + kx - 1;
        iv[rr][kx] = (oky && (unsigned)ix < 1024u)
                   ? ldin<F32>(IN, icb + (size_t)iy * 1024 + ix) : 0.f;
      }
    }
    #pragma unroll
    for (int ky = 0; ky < 3; ky++) {
      #pragma unroll
      for (int kx = 0; kx < 3; kx++) {
        const int kk = ic * 9 + ky * 3 + kx;
        const float v0 = iv[ky][kx];
        const float v1 = iv[ky + 2][kx];
        #pragma unroll
        for (int j4 = 0; j4 < 8; j4++) {
          float4 w4 = *(const float4*)&wl[kk][j4 * 4];
          a0[j4*4+0] += w4.x * v0; a0[j4*4+1] += w4.y * v0;
          a0[j4*4+2] += w4.z * v0; a0[j4*4+3] += w4.w * v0;
          a1[j4*4+0] += w4.x * v1; a1[j4*4+1] += w4.y * v1;
          a1[j4*4+2] += w4.z * v1; a1[j4*4+3] += w4.w * v1;
        }
      }
    }
  }
  const bool ok0 = (unsigned)ga < 512u;
  const bool ok1 = (unsigned)(ga + 1) < 512u;
  #pragma unroll
  for (int j = 0; j < 32; j++) {
    float v0 = ok0 ? fmaxf(a0[j], 0.f) : 0.f;
    float v1 = ok1 ? fmaxf(a1[j], 0.f) : 0.f;
    size_t base = ((size_t)(n * 64 + og * 32 + j) * L + l0) * 512 + ox;
    band[base]       = f2b(v0);
    band[base + 512] = f2b(v1);
  }
}

// ---------------------------------------------------------------------------
// conv2 band: c2o[n][oc32][r][x256], r in [rb0, rb0+BR). Band local row for
// out row r, tap ky: l = 2*(r-rb0)+ky (pad rows pre-zeroed by conv1 band).
// grid: x = BR/2 row-pairs, y = oc group(2), z = net(2)
// ---------------------------------------------------------------------------
template<int F32>
__global__ __launch_bounds__(256) void k_conv2_band(
    const bf16* __restrict__ band,
    const void* __restrict__ w0, const void* __restrict__ bi0,
    const void* __restrict__ w1, const void* __restrict__ bi1,
    bf16* __restrict__ c2o, const int* __restrict__ flag, int rb0, int L)
{
  if (flag[0] != F32) return;
  const int n  = blockIdx.z;
  const int og = blockIdx.y;
  const bf16* __restrict__ IN = band + (size_t)n * 64 * L * 512;
  const void* W = n ? w1  : w0;
  const void* B = n ? bi1 : bi0;

  __shared__ __align__(16) float wl[576][16];    // 36,864 B
  __shared__ float bl[16];
  const int tid = threadIdx.x;
  for (int i = tid; i < 9216; i += 256) {
    int ocl = i & 15, kk = i >> 4;
    wl[kk][ocl] = ldin<F32>(W, (size_t)(og * 16 + ocl) * 576 + kk);
  }
  if (tid < 16) bl[tid] = ldin<F32>(B, og * 16 + tid);
  __syncthreads();

  const int rl0 = blockIdx.x * 2;
  const int ox  = tid;

  float a0[16], a1[16];
  #pragma unroll
  for (int j = 0; j < 16; j++) { a0[j] = bl[j]; a1[j] = bl[j]; }

  for (int ic = 0; ic < 64; ic++) {
    const bf16* __restrict__ Ic = IN + (size_t)ic * L * 512;
    float iv[5][3];
    #pragma unroll
    for (int rr = 0; rr < 5; rr++) {
      const bf16* __restrict__ Ir = Ic + (size_t)(2 * rl0 + rr) * 512;
      #pragma unroll
      for (int kx = 0; kx < 3; kx++) {
        int ix = 2 * ox + kx - 1;
        iv[rr][kx] = ((unsigned)ix < 512u) ? b2f(Ir[ix]) : 0.f;
      }
    }
    #pragma unroll
    for (int ky = 0; ky < 3; ky++) {
      #pragma unroll
      for (int kx = 0; kx < 3; kx++) {
        const int kk = ic * 9 + ky * 3 + kx;
        const float v0 = iv[ky][kx];
        const float v1 = iv[ky + 2][kx];
        #pragma unroll
        for (int j4 = 0; j4 < 4; j4++) {
          float4 w4 = *(const float4*)&wl[kk][j4 * 4];
          a0[j4*4+0] += w4.x * v0; a0[j4*4+1] += w4.y * v0;
          a0[j4*4+2] += w4.z * v0; a0[j4*4+3] += w4.w * v0;
          a1[j4*4+0] += w4.x * v1; a1[j4*4+1] += w4.y * v1;
          a1[j4*4+2] += w4.z * v1; a1[j4*4+3] += w4.w * v1;
        }
      }
    }
  }
  const int r0 = rb0 + rl0;
  bf16* __restrict__ OUT = c2o + (size_t)n * 2097152;
  #pragma unroll
  for (int j = 0; j < 16; j++) {
    size_t base = (size_t)(og * 16 + j) * 65536 + (size_t)r0 * 256 + ox;
    OUT[base]       = f2b(fmaxf(a0[j], 0.f));
    OUT[base + 256] = f2b(fmaxf(a1[j], 0.f));
  }
}

// ---------------------------------------------------------------------------
// conv3: 32->16 ch, 256^2 -> 128^2, s2 p1, NO relu, fp32 out [2][16][16384]
// ---------------------------------------------------------------------------
template<int F32>
__global__ __launch_bounds__(256) void k_conv3(
    const bf16* __restrict__ in,
    const void* __restrict__ w0, const void* __restrict__ bi0,
    const void* __restrict__ w1, const void* __restrict__ bi1,
    float* __restrict__ out, const int* __restrict__ flag)
{
  if (flag[0] != F32) return;
  const int n = blockIdx.z;
  const bf16* __restrict__ IN = in + (size_t)n * 32 * 65536;
  const void* W = n ? w1  : w0;
  const void* B = n ? bi1 : bi0;
  __shared__ __align__(16) float wl[288][16];
  __shared__ float bl[16];
  const int tid = threadIdx.x;
  for (int i = tid; i < 4608; i += 256) {
    int ocl = i & 15, kk = i >> 4;
    wl[kk][ocl] = ldin<F32>(W, (size_t)ocl * 288 + kk);
  }
  if (tid < 16) bl[tid] = ldin<F32>(B, tid);
  __syncthreads();
  const int s = blockIdx.x * 256 + tid;
  const int oy = s >> 7, ox = s & 127;
  float acc[16];
  #pragma unroll
  for (int j = 0; j < 16; j++) acc[j] = bl[j];
  for (int ic = 0; ic < 32; ic++) {
    const bf16* __restrict__ Ic = IN + (size_t)ic * 65536;
    #pragma unroll
    for (int ky = 0; ky < 3; ky++) {
      int iy = 2 * oy + ky - 1;
      bool oky = (unsigned)iy < 256u;
      #pragma unroll
      for (int kx = 0; kx < 3; kx++) {
        int ix = 2 * ox + kx - 1;
        float v = (oky && (unsigned)ix < 256u) ? b2f(Ic[(long)iy * 256 + ix]) : 0.f;
        const int kk = ic * 9 + ky * 3 + kx;
        #pragma unroll
        for (int j4 = 0; j4 < 4; j4++) {
          float4 w4 = *(const float4*)&wl[kk][j4 * 4];
          acc[j4*4+0] += w4.x * v; acc[j4*4+1] += w4.y * v;
          acc[j4*4+2] += w4.z * v; acc[j4*4+3] += w4.w * v;
        }
      }
    }
  }
  float* O = out + (size_t)n * 16 * 16384;
  #pragma unroll
  for (int j = 0; j < 16; j++) O[(size_t)j * 16384 + s] = acc[j];
}

// ---------------------------------------------------------------------------
// gather + maxpool (fp32 scratch only, dtype-independent)
// ---------------------------------------------------------------------------
__global__ __launch_bounds__(256) void k_pool(
    const float* __restrict__ feat,    // [2][16][16384]
    const int* __restrict__ fgs, const int* __restrict__ fgc,
    float* __restrict__ pooled)        // [2][4096]
{
  int t = blockIdx.x * 256 + threadIdx.x;   // 0..8191
  int n = t >> 12, rem = t & 4095;
  int c = rem >> 8, p = rem & 255;
  const int* __restrict__ m = n ? fgc : fgs;
  const float* __restrict__ F = feat + (size_t)n * 16 * 16384 + (size_t)c * 16384;
  float mx = -3.4e38f;
  #pragma unroll 4
  for (int j = 0; j < 32; j++) mx = fmaxf(mx, F[m[p * 32 + j]]);
  pooled[(size_t)n * 4096 + rem] = mx;
}

// ---------------------------------------------------------------------------
// FC: mats[n][i] = fcb[i] + sum_j pooled[n][j]*fcw[i][j]
// ---------------------------------------------------------------------------
template<int F32>
__global__ __launch_bounds__(256) void k_fc(
    const float* __restrict__ pooled,
    const void* __restrict__ w0, const void* __restrict__ bb0,
    const void* __restrict__ w1, const void* __restrict__ bb1,
    float* __restrict__ mats, const int* __restrict__ flag)
{
  if (flag[0] != F32) return;
  const int n = blockIdx.z;
  const int i = blockIdx.x;
  const void* W = n ? w1  : w0;
  const void* B = n ? bb1 : bb0;
  const float* __restrict__ P = pooled + (size_t)n * 4096;
  __shared__ float red[256];
  const int tid = threadIdx.x;
  float p = 0.f;
  for (int j = tid; j < 4096; j += 256) p += P[j] * ldin<F32>(W, (size_t)i * 4096 + j);
  red[tid] = p;
  __syncthreads();
  for (int off = 128; off > 0; off >>= 1) {
    if (tid < off) red[tid] += red[tid + off];
    __syncthreads();
  }
  if (tid == 0) mats[(size_t)n * 4096 + i] = red[0] + ldin<F32>(B, i);
}

// T = sMat @ cMat  (fp32 scratch, dtype-independent)
__global__ __launch_bounds__(256) void k_tmat(
    const float* __restrict__ mats, float* __restrict__ T)
{
  int t = blockIdx.x * 256 + threadIdx.x;   // 0..4095
  int i = t >> 6, j = t & 63;
  const float* __restrict__ S = mats;
  const float* __restrict__ C = mats + 4096;
  float a = 0.f;
  #pragma unroll 8
  for (int k = 0; k < 64; k++) a += S[i * 64 + k] * C[k * 64 + j];
  T[t] = a;
}

// ---------------------------------------------------------------------------
// compress: ccf[o][s] = cb[o] + sum_c cw[o][c]*cF[c][s]  (fp32 out)
// ---------------------------------------------------------------------------
template<int F32>
__global__ __launch_bounds__(256) void k_compress(
    const void* __restrict__ cF, const void* __restrict__ cw,
    const void* __restrict__ cb, float* __restrict__ ccf,
    const int* __restrict__ flag)
{
  if (flag[0] != F32) return;
  const int og = blockIdx.y;
  __shared__ __align__(16) float wl[512][8];
  __shared__ float bl[8];
  const int tid = threadIdx.x;
  for (int i = tid; i < 4096; i += 256) {
    int ol = i & 7, c = i >> 3;
    wl[c][ol] = ldin<F32>(cw, (size_t)(og * 8 + ol) * 512 + c);
  }
  if (tid < 8) bl[tid] = ldin<F32>(cb, og * 8 + tid);
  __syncthreads();
  const int s = blockIdx.x * 256 + tid;
  float acc[8];
  #pragma unroll
  for (int j = 0; j < 8; j++) acc[j] = bl[j];
  for (int c = 0; c < 512; c++) {
    float v = ldin<F32>(cF, (size_t)c * 16384 + s);
    float4 wA = *(const float4*)&wl[c][0];
    float4 wB = *(const float4*)&wl[c][4];
    acc[0] += wA.x * v; acc[1] += wA.y * v; acc[2] += wA.z * v; acc[3] += wA.w * v;
    acc[4] += wB.x * v; acc[5] += wB.y * v; acc[6] += wB.z * v; acc[7] += wB.w * v;
  }
  #pragma unroll
  for (int j = 0; j < 8; j++) ccf[(size_t)(og * 8 + j) * 16384 + s] = acc[j];
}

__global__ __launch_bounds__(256) void k_mean(
    const float* __restrict__ ccf, float* __restrict__ mean)
{
  const int o = blockIdx.x;
  const int tid = threadIdx.x;
  __shared__ float red[256];
  const float* __restrict__ R = ccf + (size_t)o * 16384;
  float p = 0.f;
  for (int s = tid; s < 16384; s += 256) p += R[s];
  red[tid] = p;
  __syncthreads();
  for (int off = 128; off > 0; off >>= 1) {
    if (tid < off) red[tid] += red[tid + off];
    __syncthreads();
  }
  if (tid == 0) mean[o] = red[0] * (1.f / 16384.f);
}

__global__ __launch_bounds__(256) void k_scatter(
    const int* __restrict__ fgc, int* __restrict__ maskf)
{
  int t = blockIdx.x * 256 + threadIdx.x;   // 0..8191
  maskf[fgc[t]] = 1;
}

// ---------------------------------------------------------------------------
// transform -> tf bf16 (scratch-only, dtype-independent)
// ---------------------------------------------------------------------------
__global__ __launch_bounds__(256) void k_transform(
    const float* __restrict__ ccf, const float* __restrict__ Tm,
    const float* __restrict__ mean, const int* __restrict__ maskf,
    bf16* __restrict__ tf)
{
  const int og = blockIdx.y;
  __shared__ __align__(16) float Tl[16][64];
  __shared__ float ml[64];
  const int tid = threadIdx.x;
  for (int i = tid; i < 1024; i += 256) {
    int ol = i >> 6, op = i & 63;
    Tl[ol][op] = Tm[(size_t)(og * 16 + ol) * 64 + op];
  }
  if (tid < 64) ml[tid] = mean[tid];
  __syncthreads();
  const int s = blockIdx.x * 256 + tid;
  const bool msk = maskf[s] != 0;
  float col[64];
  #pragma unroll
  for (int op = 0; op < 64; op++) col[op] = ccf[(size_t)op * 16384 + s] - ml[op];
  #pragma unroll
  for (int ol = 0; ol < 16; ol++) {
    float a = 0.f;
    #pragma unroll
    for (int op4 = 0; op4 < 16; op4++) {
      float4 t4 = *(const float4*)&Tl[ol][op4 * 4];
      a += t4.x * col[op4*4+0] + t4.y * col[op4*4+1]
         + t4.z * col[op4*4+2] + t4.w * col[op4*4+3];
    }
    float un = ccf[(size_t)(og * 16 + ol) * 16384 + s] - ml[og * 16 + ol];
    tf[(size_t)(og * 16 + ol) * 16384 + s] = f2b(msk ? a : un);
  }
}

// ---------------------------------------------------------------------------
// unzip: out[u][s] = ub[u] + sum_o uw[u][o]*tf[o][s]  -> output dtype per flag
// ---------------------------------------------------------------------------
template<int F32>
__global__ __launch_bounds__(256) void k_unzip(
    const bf16* __restrict__ tf,
    const void* __restrict__ uw, const void* __restrict__ ub,
    void* __restrict__ outp, const int* __restrict__ flag)
{
  if (flag[0] != F32) return;
  const int ug = blockIdx.y;
  __shared__ __align__(16) float wl[64][32];
  __shared__ float bl[32];
  const int tid = threadIdx.x;
  for (int i = tid; i < 2048; i += 256) {
    int ul = i & 31, o = i >> 5;
    wl[o][ul] = ldin<F32>(uw, (size_t)(ug * 32 + ul) * 64 + o);
  }
  if (tid < 32) bl[tid] = ldin<F32>(ub, ug * 32 + tid);
  __syncthreads();
  const int s = blockIdx.x * 256 + tid;
  float acc[32];
  #pragma unroll
  for (int j = 0; j < 32; j++) acc[j] = bl[j];
  #pragma unroll 4
  for (int o = 0; o < 64; o++) {
    float v = b2f(tf[(size_t)o * 16384 + s]);
    #pragma unroll
    for (int j4 = 0; j4 < 8; j4++) {
      float4 w4 = *(const float4*)&wl[o][j4 * 4];
      acc[j4*4+0] += w4.x * v; acc[j4*4+1] += w4.y * v;
      acc[j4*4+2] += w4.z * v; acc[j4*4+3] += w4.w * v;
    }
  }
  #pragma unroll
  for (int j = 0; j < 32; j++) {
    size_t idx = (size_t)(ug * 32 + j) * 16384 + s;
    if (F32) ((float*)outp)[idx] = acc[j];
    else     ((bf16*)outp)[idx]  = f2b(acc[j]);
  }
}

// ---------------------------------------------------------------------------
extern "C" void kernel_launch(void* const* d_in, const int* in_sizes, int n_in,
                              void* d_out, int out_size, void* d_ws, size_t ws_size,
                              hipStream_t stream)
{
  const void* cF      = d_in[0];
  // d_in[1] = sF (unused by reference)
  const void* content = d_in[2];
  const void* style   = d_in[3];
  const void* s_c1w = d_in[4];  const void* s_c1b = d_in[5];
  const void* s_c2w = d_in[6];  const void* s_c2b = d_in[7];
  const void* s_c3w = d_in[8];  const void* s_c3b = d_in[9];
  const void* s_fcw = d_in[10]; const void* s_fcb = d_in[11];
  const void* c_c1w = d_in[12]; const void* c_c1b = d_in[13];
  const void* c_c2w = d_in[14]; const void* c_c2b = d_in[15];
  const void* c_c3w = d_in[16]; const void* c_c3b = d_in[17];
  const void* c_fcw = d_in[18]; const void* c_fcb = d_in[19];
  const void* cw = d_in[20];    const void* cb = d_in[21];
  const void* uw = d_in[22];    const void* ub = d_in[23];
  const int* fgc = (const int*)d_in[24];
  const int* fgs = (const int*)d_in[25];
  (void)in_sizes; (void)n_in; (void)out_size;

  // ---- scratch inside d_out (fits even if d_out is bf16: 14.83 MB < 16.77 MB)
  // d_out is fully rewritten by the final k_unzip, which reads nothing from it.
  char* ob = (char*)d_out;
  bf16*  c2o    = (bf16*)(ob + 0);           // [2][32][65536] bf16  8,388,608 B
  float* c3o    = (float*)(ob + 8388608);    // [2][16][16384] f32   2,097,152 B
  float* ccf    = (float*)(ob + 10485760);   // [64][16384]  f32     4,194,304 B
  float* pooled = (float*)(ob + 14680064);   // [2][4096]               32,768 B
  float* mats   = (float*)(ob + 14712832);   // [2][4096]               32,768 B
  float* T      = (float*)(ob + 14745600);   // [64][64]                16,384 B
  float* mean   = (float*)(ob + 14761984);   // [64]+pad                 1,024 B
  int*   maskf  = (int*)(ob + 14763008);     // [16384]                 65,536 B
  int*   flag   = (int*)(ob + 14828544);     // dtype flag                  16 B

  // ---- d_ws: conv1 band (bf16), then tf reuses the dead band region
  bf16* band = (bf16*)d_ws;
  bf16* tf   = (bf16*)d_ws;                  // [64][16384] bf16, 2,097,152 B

  // adaptive band count: band bytes = 131072 * (512/nb + 2)
  int nb;
  if      (ws_size >= 17039360u) nb = 4;     // L=130
  else if (ws_size >= 8650752u)  nb = 8;     // L=66
  else if (ws_size >= 4456448u)  nb = 16;    // L=34
  else                           nb = 32;    // L=18, 2.36 MB
  const int BR = 256 / nb;
  const int L  = 2 * BR + 2;

  // ---- dtype detection + column mask ----
  k_detect<<<1, 64, 0, stream>>>((const unsigned short*)cF, flag);
  (void)hipMemsetAsync(maskf, 0, 16384 * sizeof(int), stream);
  k_scatter<<<32, 256, 0, stream>>>(fgc, maskf);

  // ---- two CNNs, banded conv1->conv2 ----
  for (int b = 0; b < nb; b++) {
    const int rb0 = b * BR;
    const int g0  = 2 * rb0 - 1;
    k_conv1_band<0><<<dim3(L, 2, 2), 256, 0, stream>>>(
        style, content, s_c1w, s_c1b, c_c1w, c_c1b, band, flag, g0, L);
    k_conv1_band<1><<<dim3(L, 2, 2), 256, 0, stream>>>(
        style, content, s_c1w, s_c1b, c_c1w, c_c1b, band, flag, g0, L);
    k_conv2_band<0><<<dim3(BR / 2, 2, 2), 256, 0, stream>>>(
        band, s_c2w, s_c2b, c_c2w, c_c2b, c2o, flag, rb0, L);
    k_conv2_band<1><<<dim3(BR / 2, 2, 2), 256, 0, stream>>>(
        band, s_c2w, s_c2b, c_c2w, c_c2b, c2o, flag, rb0, L);
  }
  k_conv3<0><<<dim3(64, 1, 2), 256, 0, stream>>>(c2o, s_c3w, s_c3b, c_c3w, c_c3b, c3o, flag);
  k_conv3<1><<<dim3(64, 1, 2), 256, 0, stream>>>(c2o, s_c3w, s_c3b, c_c3w, c_c3b, c3o, flag);
  k_pool<<<32, 256, 0, stream>>>(c3o, fgs, fgc, pooled);
  k_fc<0><<<dim3(4096, 1, 2), 256, 0, stream>>>(pooled, s_fcw, s_fcb, c_fcw, c_fcb, mats, flag);
  k_fc<1><<<dim3(4096, 1, 2), 256, 0, stream>>>(pooled, s_fcw, s_fcb, c_fcw, c_fcb, mats, flag);
  k_tmat<<<16, 256, 0, stream>>>(mats, T);

  // ---- feature path ----
  k_compress<0><<<dim3(64, 8), 256, 0, stream>>>(cF, cw, cb, ccf, flag);
  k_compress<1><<<dim3(64, 8), 256, 0, stream>>>(cF, cw, cb, ccf, flag);
  k_mean<<<64, 256, 0, stream>>>(ccf, mean);
  k_transform<<<dim3(64, 4), 256, 0, stream>>>(ccf, T, mean, maskf, tf);
  k_unzip<0><<<dim3(64, 16), 256, 0, stream>>>(tf, uw, ub, d_out, flag);
  k_unzip<1><<<dim3(64, 16), 256, 0, stream>>>(tf, uw, ub, d_out, flag);
}

// Round 4
// 837.814 us; speedup vs baseline: 1.3402x; 1.3402x over previous
//
#include <hip/hip_runtime.h>
#include <hip/hip_bf16.h>

typedef __hip_bfloat16 bf16;

__device__ __forceinline__ float b2f(bf16 v) { return __bfloat162float(v); }
__device__ __forceinline__ bf16  f2b(float v) { return __float2bfloat16(v); }

// dtype-flexible input load: F32=1 -> float*, F32=0 -> bf16*
template<int F32>
__device__ __forceinline__ float ldin(const void* p, size_t i) {
  if (F32) return ((const float*)p)[i];
  return b2f(((const bf16*)p)[i]);
}

// ---------------------------------------------------------------------------
// dtype detector: bf16 N(0,1) data never has exponent field >= 0x90 (|x|>=2^17);
// fp32-as-u16 low halves are random -> ~44% exceed it. flag=1 means fp32.
// ---------------------------------------------------------------------------
__global__ void k_detect(const unsigned short* __restrict__ u, int* __restrict__ flag)
{
  if (threadIdx.x == 0 && blockIdx.x == 0) {
    int nbad = 0;
    for (int i = 0; i < 256; i++) {
      unsigned e = (u[i] >> 7) & 0xFFu;
      nbad += (e >= 0x90u) ? 1 : 0;
    }
    flag[0] = (nbad > 8) ? 1 : 0;
  }
}

// ---------------------------------------------------------------------------
// FUSED conv1+conv2. Per block: conv2 out tile 32 rows x 16 cols x 16 oc.
// conv1 tile (66 rows x 34 cols) computed slice-by-slice (8 of 64 ch) in LDS.
// grid: x = col tile (16), y = (row tile(8) << 1) | og(2), z = net(2)
//   -> 512 blocks, ~49.9 KB LDS, 2 blocks/CU resident.
// ---------------------------------------------------------------------------
template<int F32>
__global__ __launch_bounds__(256) void k_conv12(
    const void* __restrict__ in0, const void* __restrict__ in1,   // [3][1024][1024]
    const void* __restrict__ w1_0, const void* __restrict__ b1_0,
    const void* __restrict__ w1_1, const void* __restrict__ b1_1,
    const void* __restrict__ w2_0, const void* __restrict__ b2_0,
    const void* __restrict__ w2_1, const void* __restrict__ b2_1,
    bf16* __restrict__ c2o, const int* __restrict__ flag)
{
  if (flag[0] != F32) return;
  const int n   = blockIdx.z;
  const int og  = blockIdx.y & 1;          // 16-oc group
  const int ty  = blockIdx.y >> 1;         // row tile 0..7
  const int tx  = blockIdx.x;              // col tile 0..15
  const int R0  = ty * 32;                 // conv2 out rows R0..R0+31
  const int C0  = tx * 16;                 // conv2 out cols C0..C0+15
  const void* IN = n ? in1 : in0;          // n=0: style/snet, n=1: content/cnet
  const void* W1 = n ? w1_1 : w1_0;
  const void* B1 = n ? b1_1 : b1_0;
  const void* W2 = n ? w2_1 : w2_0;
  const void* B2 = n ? b2_1 : b2_0;

  __shared__ bf16  c1s[8][66][36];         // conv1 slice tile (34 cols used) 38,016 B
  __shared__ float w1a[64][27];            //  6,912 B  (all conv1 weights)
  __shared__ float b1a[64];                //    256 B
  __shared__ __align__(16) float w2s[72][16]; // 4,608 B (per-slice conv2 w)
  __shared__ float b2s[16];                //     64 B

  const int tid = threadIdx.x;

  // ---- one-time staging: conv1 weights/bias (all 64 ch), conv2 bias ----
  for (int i = tid; i < 1728; i += 256) {  // 64*27
    int ch = i / 27, k = i - ch * 27;
    w1a[ch][k] = ldin<F32>(W1, (size_t)ch * 27 + k);
  }
  if (tid < 64) b1a[tid] = ldin<F32>(B1, tid);
  if (tid < 16) b2s[tid] = ldin<F32>(B2, og * 16 + tid);
  __syncthreads();

  // ---- conv2 accumulators: 2 rows x 16 oc per thread ----
  const int rp = tid >> 4;                 // 0..15 (row pair)
  const int cc = tid & 15;                 // 0..15 (col)
  float a0[16], a1[16];
  #pragma unroll
  for (int j = 0; j < 16; j++) { a0[j] = b2s[j]; a1[j] = b2s[j]; }

  for (int ss = 0; ss < 8; ss++) {         // conv1-channel slices of 8
    if (ss > 0) __syncthreads();           // prev phase-B done with c1s/w2s

    // ---- stage conv2 weights for this slice: w2s[icl*9+tap][ocl] ----
    for (int i = tid; i < 1152; i += 256) {           // 72*16
      int ocl = i & 15, kk = i >> 4;                  // kk = icl*9+tap
      w2s[kk][ocl] = ldin<F32>(W2,
          (size_t)(og * 16 + ocl) * 576 + (size_t)ss * 72 + kk);
    }

    // ---- phase A: conv1 slice (8 ch) into LDS ----
    for (int i = tid; i < 2244; i += 256) {           // 66*34 positions
      const int lr = i / 34, lc = i - lr * 34;
      const int gr = 2 * R0 - 1 + lr;                 // conv1 global row
      const int gc = 2 * C0 - 1 + lc;                 // conv1 global col
      float acc1[8];
      if ((unsigned)gr < 512u && (unsigned)gc < 512u) {
        #pragma unroll
        for (int ch = 0; ch < 8; ch++) acc1[ch] = b1a[ss * 8 + ch];
        #pragma unroll
        for (int icc = 0; icc < 3; icc++) {
          const size_t icb = (size_t)icc * 1048576;
          #pragma unroll
          for (int ky = 0; ky < 3; ky++) {
            const int iy = 2 * gr - 1 + ky;
            const bool oky = (unsigned)iy < 1024u;
            #pragma unroll
            for (int kx = 0; kx < 3; kx++) {
              const int ix = 2 * gc - 1 + kx;
              const float v = (oky && (unsigned)ix < 1024u)
                            ? ldin<F32>(IN, icb + (size_t)iy * 1024 + ix) : 0.f;
              const int k = icc * 9 + ky * 3 + kx;
              #pragma unroll
              for (int ch = 0; ch < 8; ch++)
                acc1[ch] += w1a[ss * 8 + ch][k] * v;
            }
          }
        }
        #pragma unroll
        for (int ch = 0; ch < 8; ch++)
          c1s[ch][lr][lc] = f2b(fmaxf(acc1[ch], 0.f));   // ReLU
      } else {
        #pragma unroll
        for (int ch = 0; ch < 8; ch++) c1s[ch][lr][lc] = f2b(0.f);  // zero pad
      }
    }
    __syncthreads();

    // ---- phase B: conv2 accumulate from LDS slice ----
    #pragma unroll 2
    for (int icl = 0; icl < 8; icl++) {
      float iv[5][3];
      #pragma unroll
      for (int rr = 0; rr < 5; rr++) {
        #pragma unroll
        for (int kx = 0; kx < 3; kx++)
          iv[rr][kx] = b2f(c1s[icl][4 * rp + rr][2 * cc + kx]);
      }
      #pragma unroll
      for (int ky = 0; ky < 3; ky++) {
        #pragma unroll
        for (int kx = 0; kx < 3; kx++) {
          const int kk = icl * 9 + ky * 3 + kx;
          const float v0 = iv[ky][kx];
          const float v1 = iv[ky + 2][kx];
          #pragma unroll
          for (int j4 = 0; j4 < 4; j4++) {
            float4 w4 = *(const float4*)&w2s[kk][j4 * 4];
            a0[j4*4+0] += w4.x * v0; a0[j4*4+1] += w4.y * v0;
            a0[j4*4+2] += w4.z * v0; a0[j4*4+3] += w4.w * v0;
            a1[j4*4+0] += w4.x * v1; a1[j4*4+1] += w4.y * v1;
            a1[j4*4+2] += w4.z * v1; a1[j4*4+3] += w4.w * v1;
          }
        }
      }
    }
  }

  // ---- store conv2 out tile (ReLU) ----
  bf16* __restrict__ OUT = c2o + (size_t)n * 2097152;
  const size_t sp0 = (size_t)(R0 + 2 * rp) * 256 + (C0 + cc);
  #pragma unroll
  for (int j = 0; j < 16; j++) {
    const size_t base = (size_t)(og * 16 + j) * 65536 + sp0;
    OUT[base]       = f2b(fmaxf(a0[j], 0.f));
    OUT[base + 256] = f2b(fmaxf(a1[j], 0.f));
  }
}

// ---------------------------------------------------------------------------
// conv3: 32->16 ch, 256^2 -> 128^2, s2 p1, NO relu, fp32 out [2][16][16384]
// ---------------------------------------------------------------------------
template<int F32>
__global__ __launch_bounds__(256) void k_conv3(
    const bf16* __restrict__ in,
    const void* __restrict__ w0, const void* __restrict__ bi0,
    const void* __restrict__ w1, const void* __restrict__ bi1,
    float* __restrict__ out, const int* __restrict__ flag)
{
  if (flag[0] != F32) return;
  const int n = blockIdx.z;
  const bf16* __restrict__ IN = in + (size_t)n * 32 * 65536;
  const void* W = n ? w1  : w0;
  const void* B = n ? bi1 : bi0;
  __shared__ __align__(16) float wl[288][16];
  __shared__ float bl[16];
  const int tid = threadIdx.x;
  for (int i = tid; i < 4608; i += 256) {
    int ocl = i & 15, kk = i >> 4;
    wl[kk][ocl] = ldin<F32>(W, (size_t)ocl * 288 + kk);
  }
  if (tid < 16) bl[tid] = ldin<F32>(B, tid);
  __syncthreads();
  const int s = blockIdx.x * 256 + tid;
  const int oy = s >> 7, ox = s & 127;
  float acc[16];
  #pragma unroll
  for (int j = 0; j < 16; j++) acc[j] = bl[j];
  for (int ic = 0; ic < 32; ic++) {
    const bf16* __restrict__ Ic = IN + (size_t)ic * 65536;
    #pragma unroll
    for (int ky = 0; ky < 3; ky++) {
      int iy = 2 * oy + ky - 1;
      bool oky = (unsigned)iy < 256u;
      #pragma unroll
      for (int kx = 0; kx < 3; kx++) {
        int ix = 2 * ox + kx - 1;
        float v = (oky && (unsigned)ix < 256u) ? b2f(Ic[(long)iy * 256 + ix]) : 0.f;
        const int kk = ic * 9 + ky * 3 + kx;
        #pragma unroll
        for (int j4 = 0; j4 < 4; j4++) {
          float4 w4 = *(const float4*)&wl[kk][j4 * 4];
          acc[j4*4+0] += w4.x * v; acc[j4*4+1] += w4.y * v;
          acc[j4*4+2] += w4.z * v; acc[j4*4+3] += w4.w * v;
        }
      }
    }
  }
  float* O = out + (size_t)n * 16 * 16384;
  #pragma unroll
  for (int j = 0; j < 16; j++) O[(size_t)j * 16384 + s] = acc[j];
}

// ---------------------------------------------------------------------------
// gather + maxpool (fp32 scratch only, dtype-independent)
// ---------------------------------------------------------------------------
__global__ __launch_bounds__(256) void k_pool(
    const float* __restrict__ feat,    // [2][16][16384]
    const int* __restrict__ fgs, const int* __restrict__ fgc,
    float* __restrict__ pooled)        // [2][4096]
{
  int t = blockIdx.x * 256 + threadIdx.x;   // 0..8191
  int n = t >> 12, rem = t & 4095;
  int c = rem >> 8, p = rem & 255;
  const int* __restrict__ m = n ? fgc : fgs;
  const float* __restrict__ F = feat + (size_t)n * 16 * 16384 + (size_t)c * 16384;
  float mx = -3.4e38f;
  #pragma unroll 4
  for (int j = 0; j < 32; j++) mx = fmaxf(mx, F[m[p * 32 + j]]);
  pooled[(size_t)n * 4096 + rem] = mx;
}

// ---------------------------------------------------------------------------
// FC: mats[n][i] = fcb[i] + sum_j pooled[n][j]*fcw[i][j]
// ---------------------------------------------------------------------------
template<int F32>
__global__ __launch_bounds__(256) void k_fc(
    const float* __restrict__ pooled,
    const void* __restrict__ w0, const void* __restrict__ bb0,
    const void* __restrict__ w1, const void* __restrict__ bb1,
    float* __restrict__ mats, const int* __restrict__ flag)
{
  if (flag[0] != F32) return;
  const int n = blockIdx.z;
  const int i = blockIdx.x;
  const void* W = n ? w1  : w0;
  const void* B = n ? bb1 : bb0;
  const float* __restrict__ P = pooled + (size_t)n * 4096;
  __shared__ float red[256];
  const int tid = threadIdx.x;
  float p = 0.f;
  for (int j = tid; j < 4096; j += 256) p += P[j] * ldin<F32>(W, (size_t)i * 4096 + j);
  red[tid] = p;
  __syncthreads();
  for (int off = 128; off > 0; off >>= 1) {
    if (tid < off) red[tid] += red[tid + off];
    __syncthreads();
  }
  if (tid == 0) mats[(size_t)n * 4096 + i] = red[0] + ldin<F32>(B, i);
}

// T = sMat @ cMat  (fp32 scratch, dtype-independent)
__global__ __launch_bounds__(256) void k_tmat(
    const float* __restrict__ mats, float* __restrict__ T)
{
  int t = blockIdx.x * 256 + threadIdx.x;   // 0..4095
  int i = t >> 6, j = t & 63;
  const float* __restrict__ S = mats;
  const float* __restrict__ C = mats + 4096;
  float a = 0.f;
  #pragma unroll 8
  for (int k = 0; k < 64; k++) a += S[i * 64 + k] * C[k * 64 + j];
  T[t] = a;
}

// ---------------------------------------------------------------------------
// compress: ccf[o][s] = cb[o] + sum_c cw[o][c]*cF[c][s]  (fp32 out)
// ---------------------------------------------------------------------------
template<int F32>
__global__ __launch_bounds__(256) void k_compress(
    const void* __restrict__ cF, const void* __restrict__ cw,
    const void* __restrict__ cb, float* __restrict__ ccf,
    const int* __restrict__ flag)
{
  if (flag[0] != F32) return;
  const int og = blockIdx.y;
  __shared__ __align__(16) float wl[512][8];
  __shared__ float bl[8];
  const int tid = threadIdx.x;
  for (int i = tid; i < 4096; i += 256) {
    int ol = i & 7, c = i >> 3;
    wl[c][ol] = ldin<F32>(cw, (size_t)(og * 8 + ol) * 512 + c);
  }
  if (tid < 8) bl[tid] = ldin<F32>(cb, og * 8 + tid);
  __syncthreads();
  const int s = blockIdx.x * 256 + tid;
  float acc[8];
  #pragma unroll
  for (int j = 0; j < 8; j++) acc[j] = bl[j];
  for (int c = 0; c < 512; c++) {
    float v = ldin<F32>(cF, (size_t)c * 16384 + s);
    float4 wA = *(const float4*)&wl[c][0];
    float4 wB = *(const float4*)&wl[c][4];
    acc[0] += wA.x * v; acc[1] += wA.y * v; acc[2] += wA.z * v; acc[3] += wA.w * v;
    acc[4] += wB.x * v; acc[5] += wB.y * v; acc[6] += wB.z * v; acc[7] += wB.w * v;
  }
  #pragma unroll
  for (int j = 0; j < 8; j++) ccf[(size_t)(og * 8 + j) * 16384 + s] = acc[j];
}

__global__ __launch_bounds__(256) void k_mean(
    const float* __restrict__ ccf, float* __restrict__ mean)
{
  const int o = blockIdx.x;
  const int tid = threadIdx.x;
  __shared__ float red[256];
  const float* __restrict__ R = ccf + (size_t)o * 16384;
  float p = 0.f;
  for (int s = tid; s < 16384; s += 256) p += R[s];
  red[tid] = p;
  __syncthreads();
  for (int off = 128; off > 0; off >>= 1) {
    if (tid < off) red[tid] += red[tid + off];
    __syncthreads();
  }
  if (tid == 0) mean[o] = red[0] * (1.f / 16384.f);
}

__global__ __launch_bounds__(256) void k_scatter(
    const int* __restrict__ fgc, int* __restrict__ maskf)
{
  int t = blockIdx.x * 256 + threadIdx.x;   // 0..8191
  maskf[fgc[t]] = 1;
}

// ---------------------------------------------------------------------------
// transform -> tf bf16 (scratch-only, dtype-independent)
// ---------------------------------------------------------------------------
__global__ __launch_bounds__(256) void k_transform(
    const float* __restrict__ ccf, const float* __restrict__ Tm,
    const float* __restrict__ mean, const int* __restrict__ maskf,
    bf16* __restrict__ tf)
{
  const int og = blockIdx.y;
  __shared__ __align__(16) float Tl[16][64];
  __shared__ float ml[64];
  const int tid = threadIdx.x;
  for (int i = tid; i < 1024; i += 256) {
    int ol = i >> 6, op = i & 63;
    Tl[ol][op] = Tm[(size_t)(og * 16 + ol) * 64 + op];
  }
  if (tid < 64) ml[tid] = mean[tid];
  __syncthreads();
  const int s = blockIdx.x * 256 + tid;
  const bool msk = maskf[s] != 0;
  float col[64];
  #pragma unroll
  for (int op = 0; op < 64; op++) col[op] = ccf[(size_t)op * 16384 + s] - ml[op];
  #pragma unroll
  for (int ol = 0; ol < 16; ol++) {
    float a = 0.f;
    #pragma unroll
    for (int op4 = 0; op4 < 16; op4++) {
      float4 t4 = *(const float4*)&Tl[ol][op4 * 4];
      a += t4.x * col[op4*4+0] + t4.y * col[op4*4+1]
         + t4.z * col[op4*4+2] + t4.w * col[op4*4+3];
    }
    float un = ccf[(size_t)(og * 16 + ol) * 16384 + s] - ml[og * 16 + ol];
    tf[(size_t)(og * 16 + ol) * 16384 + s] = f2b(msk ? a : un);
  }
}

// ---------------------------------------------------------------------------
// unzip: out[u][s] = ub[u] + sum_o uw[u][o]*tf[o][s]  -> output dtype per flag
// ---------------------------------------------------------------------------
template<int F32>
__global__ __launch_bounds__(256) void k_unzip(
    const bf16* __restrict__ tf,
    const void* __restrict__ uw, const void* __restrict__ ub,
    void* __restrict__ outp, const int* __restrict__ flag)
{
  if (flag[0] != F32) return;
  const int ug = blockIdx.y;
  __shared__ __align__(16) float wl[64][32];
  __shared__ float bl[32];
  const int tid = threadIdx.x;
  for (int i = tid; i < 2048; i += 256) {
    int ul = i & 31, o = i >> 5;
    wl[o][ul] = ldin<F32>(uw, (size_t)(ug * 32 + ul) * 64 + o);
  }
  if (tid < 32) bl[tid] = ldin<F32>(ub, ug * 32 + tid);
  __syncthreads();
  const int s = blockIdx.x * 256 + tid;
  float acc[32];
  #pragma unroll
  for (int j = 0; j < 32; j++) acc[j] = bl[j];
  #pragma unroll 4
  for (int o = 0; o < 64; o++) {
    float v = b2f(tf[(size_t)o * 16384 + s]);
    #pragma unroll
    for (int j4 = 0; j4 < 8; j4++) {
      float4 w4 = *(const float4*)&wl[o][j4 * 4];
      acc[j4*4+0] += w4.x * v; acc[j4*4+1] += w4.y * v;
      acc[j4*4+2] += w4.z * v; acc[j4*4+3] += w4.w * v;
    }
  }
  #pragma unroll
  for (int j = 0; j < 32; j++) {
    size_t idx = (size_t)(ug * 32 + j) * 16384 + s;
    if (F32) ((float*)outp)[idx] = acc[j];
    else     ((bf16*)outp)[idx]  = f2b(acc[j]);
  }
}

// ---------------------------------------------------------------------------
extern "C" void kernel_launch(void* const* d_in, const int* in_sizes, int n_in,
                              void* d_out, int out_size, void* d_ws, size_t ws_size,
                              hipStream_t stream)
{
  const void* cF      = d_in[0];
  // d_in[1] = sF (unused by reference)
  const void* content = d_in[2];
  const void* style   = d_in[3];
  const void* s_c1w = d_in[4];  const void* s_c1b = d_in[5];
  const void* s_c2w = d_in[6];  const void* s_c2b = d_in[7];
  const void* s_c3w = d_in[8];  const void* s_c3b = d_in[9];
  const void* s_fcw = d_in[10]; const void* s_fcb = d_in[11];
  const void* c_c1w = d_in[12]; const void* c_c1b = d_in[13];
  const void* c_c2w = d_in[14]; const void* c_c2b = d_in[15];
  const void* c_c3w = d_in[16]; const void* c_c3b = d_in[17];
  const void* c_fcw = d_in[18]; const void* c_fcb = d_in[19];
  const void* cw = d_in[20];    const void* cb = d_in[21];
  const void* uw = d_in[22];    const void* ub = d_in[23];
  const int* fgc = (const int*)d_in[24];
  const int* fgs = (const int*)d_in[25];
  (void)in_sizes; (void)n_in; (void)out_size; (void)ws_size;

  // ---- scratch inside d_out (14.83 MB < 16.77 MB bf16 d_out); d_out fully
  // rewritten by the final k_unzip which reads nothing from it.
  char* ob = (char*)d_out;
  bf16*  c2o    = (bf16*)(ob + 0);           // [2][32][65536] bf16  8,388,608 B
  float* c3o    = (float*)(ob + 8388608);    // [2][16][16384] f32   2,097,152 B
  float* ccf    = (float*)(ob + 10485760);   // [64][16384]  f32     4,194,304 B
  float* pooled = (float*)(ob + 14680064);   // [2][4096]               32,768 B
  float* mats   = (float*)(ob + 14712832);   // [2][4096]               32,768 B
  float* T      = (float*)(ob + 14745600);   // [64][64]                16,384 B
  float* mean   = (float*)(ob + 14761984);   // [64]+pad                 1,024 B
  int*   maskf  = (int*)(ob + 14763008);     // [16384]                 65,536 B
  int*   flag   = (int*)(ob + 14828544);     // dtype flag                  16 B

  // ---- d_ws: only tf (2,097,152 B) ----
  bf16* tf = (bf16*)d_ws;

  // ---- dtype detection + column mask ----
  k_detect<<<1, 64, 0, stream>>>((const unsigned short*)cF, flag);
  (void)hipMemsetAsync(maskf, 0, 16384 * sizeof(int), stream);
  k_scatter<<<32, 256, 0, stream>>>(fgc, maskf);

  // ---- fused conv1+conv2 (both nets, one launch per dtype variant) ----
  k_conv12<0><<<dim3(16, 16, 2), 256, 0, stream>>>(
      style, content, s_c1w, s_c1b, c_c1w, c_c1b,
      s_c2w, s_c2b, c_c2w, c_c2b, c2o, flag);
  k_conv12<1><<<dim3(16, 16, 2), 256, 0, stream>>>(
      style, content, s_c1w, s_c1b, c_c1w, c_c1b,
      s_c2w, s_c2b, c_c2w, c_c2b, c2o, flag);

  k_conv3<0><<<dim3(64, 1, 2), 256, 0, stream>>>(c2o, s_c3w, s_c3b, c_c3w, c_c3b, c3o, flag);
  k_conv3<1><<<dim3(64, 1, 2), 256, 0, stream>>>(c2o, s_c3w, s_c3b, c_c3w, c_c3b, c3o, flag);
  k_pool<<<32, 256, 0, stream>>>(c3o, fgs, fgc, pooled);
  k_fc<0><<<dim3(4096, 1, 2), 256, 0, stream>>>(pooled, s_fcw, s_fcb, c_fcw, c_fcb, mats, flag);
  k_fc<1><<<dim3(4096, 1, 2), 256, 0, stream>>>(pooled, s_fcw, s_fcb, c_fcw, c_fcb, mats, flag);
  k_tmat<<<16, 256, 0, stream>>>(mats, T);

  // ---- feature path ----
  k_compress<0><<<dim3(64, 8), 256, 0, stream>>>(cF, cw, cb, ccf, flag);
  k_compress<1><<<dim3(64, 8), 256, 0, stream>>>(cF, cw, cb, ccf, flag);
  k_mean<<<64, 256, 0, stream>>>(ccf, mean);
  k_transform<<<dim3(64, 4), 256, 0, stream>>>(ccf, T, mean, maskf, tf);
  k_unzip<0><<<dim3(64, 16), 256, 0, stream>>>(tf, uw, ub, d_out, flag);
  k_unzip<1><<<dim3(64, 16), 256, 0, stream>>>(tf, uw, ub, d_out, flag);
}